// Round 9
// baseline (6474.768 us; speedup 1.0000x reference)
//
#include <hip/hip_runtime.h>
#include <hip/hip_fp16.h>
#include <math.h>

// Problem constants
#define S1 256
#define S2 256
#define S3 128
#define DV 8
#define NK1 30
#define NK2 30
#define NK3 20
#define NPEN (S1*S2)          // 65536 pencils along x3
#define PENC (S3*DV)          // 1024 elements per v pencil (fp16)
#define GPEN (DV*NK3)         // 160 complex per g pencil (fp16 complex)
#define HSLICE (NK2*DV*NK3)   // 4800 complex per x1 slice of h (fp32)
#define PB 4                  // pencils per block in combine/shallow/final

// vnf LDS layout: [PB][DV][VNF_D] floats, parity plane at par*VNF_P
#define VNF_D 148
#define VNF_P 72

// Workspace layout in float-slots (4 bytes each) — total ~179.7 MiB
#define OFF_V     0ull
#define SZ_V      ((unsigned long long)NPEN*PENC/2)
#define OFF_G     (OFF_V + SZ_V)
#define SZ_G      ((unsigned long long)NPEN*GPEN)
#define OFF_H     (OFF_G + SZ_G)
#define SZ_H      ((unsigned long long)S1*HSLICE*2)
#define OFF_F     (OFF_H + SZ_H)
#define SZ_F      ((unsigned long long)NK1*HSLICE*2)
#define OFF_RF    (OFF_F + SZ_F)
#define OFF_TW128 (OFF_RF + SZ_F)
#define SZ_TW128  (2ull*NK3*64)
#define OFF_TW256 (OFF_TW128 + SZ_TW128)

__device__ __forceinline__ float gelu_f(float x){
  return 0.5f*x*(1.0f+erff(x*0.70710678118654752440f));
}
__device__ __forceinline__ void cmac_fwd(float& ar, float& ai, float2 a, float2 t){
  ar = fmaf(a.x, t.x, ar); ar = fmaf(-a.y, t.y, ar);
  ai = fmaf(a.x, t.y, ai); ai = fmaf(a.y, t.x, ai);
}
__device__ __forceinline__ void cmac_inv(float& ar, float& ai, float2 a, float2 t){
  ar = fmaf(a.x, t.x, ar); ar = fmaf(a.y, t.y, ar);
  ai = fmaf(a.y, t.x, ai); ai = fmaf(-a.x, t.y, ai);
}
__device__ __forceinline__ uint4 pack_h8(const float* v8){
  union { uint4 u4; __half2 h2[4]; } u;
  u.h2[0] = __floats2half2_rn(v8[0], v8[1]);
  u.h2[1] = __floats2half2_rn(v8[2], v8[3]);
  u.h2[2] = __floats2half2_rn(v8[4], v8[5]);
  u.h2[3] = __floats2half2_rn(v8[6], v8[7]);
  return u.u4;
}
__device__ __forceinline__ void unpack_h8(uint4 u4in, float* v8){
  union { uint4 u4; __half2 h2[4]; } u; u.u4 = u4in;
  #pragma unroll
  for (int q=0;q<4;q++){
    float2 f2 = __half22float2(u.h2[q]);
    v8[2*q] = f2.x; v8[2*q+1] = f2.y;
  }
}

// ---------------------------------------------------------------- twiddles
// tw128: [20][64] e^{-2pi i k x/128}, x<64 ; tw256: [30][256]
__global__ __launch_bounds__(256) void k_twiddles(float2* __restrict__ tw128,
                                                  float2* __restrict__ tw256){
  int idx = blockIdx.x*256 + threadIdx.x;
  if (idx < NK3*64){
    int k = idx >> 6, x = idx & 63;
    int m = (k*x) & 127;
    float a = -(float)m * (1.0f/64.0f);
    float s, c; sincospif(a, &s, &c);
    tw128[idx] = make_float2(c, s);   // (cos, -sin)
  }
  int j = idx - NK3*64;
  if (j >= 0 && j < NK2*S2){
    int k = j >> 8, x = j & 255;
    int m = (k*x) & 255;
    float a = -(float)m * (1.0f/128.0f);
    float s, c; sincospif(a, &s, &c);
    tw256[j] = make_float2(c, s);
  }
}

// =========================================================================
// fwd axis-2 DFT from folded vnf -> g, lanes 0..39 of each warp
// X[k3] = sum_{x<64} w_par[x] e^{-2pi i k3 x/128},  par = k3&1
// =========================================================================
__device__ __forceinline__ void fwd_dft_phase(const float (*vnfp)[VNF_D],
    const float2* tws, __half2* gout_pen, int l){
  if (l >= 40) return;
  int k3 = l % 20, dg = l / 20, par = k3 & 1;
  float ar[4] = {0,0,0,0}, ai[4] = {0,0,0,0};
  for (int x0 = 0; x0 < 64; x0 += 4){
    float4 vv[4];
    #pragma unroll
    for (int di=0; di<4; di++)
      vv[di] = *reinterpret_cast<const float4*>(&vnfp[dg*4+di][par*VNF_P + x0]);
    float2 t2[4];
    #pragma unroll
    for (int xi=0; xi<4; xi++) t2[xi] = tws[k3*67 + x0 + xi];
    #pragma unroll
    for (int di=0; di<4; di++){
      ar[di] = fmaf(vv[di].x, t2[0].x, ar[di]); ai[di] = fmaf(vv[di].x, t2[0].y, ai[di]);
      ar[di] = fmaf(vv[di].y, t2[1].x, ar[di]); ai[di] = fmaf(vv[di].y, t2[1].y, ai[di]);
      ar[di] = fmaf(vv[di].z, t2[2].x, ar[di]); ai[di] = fmaf(vv[di].z, t2[2].y, ai[di]);
      ar[di] = fmaf(vv[di].w, t2[3].x, ar[di]); ai[di] = fmaf(vv[di].w, t2[3].y, ai[di]);
    }
  }
  #pragma unroll
  for (int di=0; di<4; di++)
    gout_pen[(dg*4+di)*NK3 + k3] = __floats2half2_rn(ar[di], ai[di]);
}

// ------------------------------------------------- shallow lift + axis-2 DFT
// lane l owns x3 = l and l+64, all 8 channels
__global__ __launch_bounds__(256,2) void k_shallow(const float* __restrict__ x,
    const float* __restrict__ sw, const float* __restrict__ sb,
    __half* __restrict__ v, __half2* __restrict__ g,
    const float2* __restrict__ twg){
  __shared__ float2 tws[NK3*67];
  __shared__ float  vnf[PB][DV][VNF_D];
  int t = threadIdx.x;
  size_t pen_base = (size_t)blockIdx.x * PB;
  for (int i=t; i<NK3*64; i+=256){ int k=i>>6, xx=i&63; tws[k*67+xx] = twg[i]; }
  int p = t >> 6, l = t & 63;
  size_t pen = pen_base + p;
  float xA = x[(pen<<7) + l];
  float xB = x[(pen<<7) + l + 64];
  float valA[8], valB[8];
  #pragma unroll
  for (int e=0;e<8;e++){
    float we = sw[e], be = sb[e];            // uniform -> scalar loads
    valA[e] = gelu_f(fmaf(xA, we, be));
    valB[e] = gelu_f(fmaf(xB, we, be));
  }
  *reinterpret_cast<uint4*>(v + (pen<<10) + l*8)        = pack_h8(valA);
  *reinterpret_cast<uint4*>(v + (pen<<10) + (l+64)*8)   = pack_h8(valB);
  #pragma unroll
  for (int e=0;e<8;e++){
    vnf[p][e][l]          = valA[e] + valB[e];
    vnf[p][e][VNF_P + l]  = valA[e] - valB[e];
  }
  __syncthreads();
  fwd_dft_phase(vnf[p], tws, g + pen*GPEN, l);
}

// --------------------- combine: inv axis-2 DFT + skip + GELU + next fwd DFT
__global__ __launch_bounds__(256,2) void k_combine(__half* __restrict__ v,
    __half2* __restrict__ g, const float* __restrict__ w,
    const float2* __restrict__ twg){
  __shared__ float2 tws[NK3*67];
  __shared__ float  vnf[PB][DV][VNF_D];
  __shared__ float2 Gsm[PB][GPEN];   // transposed: [k3*8 + e], x2-scaled for k3>0
  __shared__ float  wsm[64];
  int t = threadIdx.x;
  size_t pen_base = (size_t)blockIdx.x * PB;
  for (int i=t; i<NK3*64; i+=256){ int k=i>>6, xx=i&63; tws[k*67+xx] = twg[i]; }
  {
    const __half2* gsrc = g + pen_base*GPEN;
    for (int i=t; i<PB*GPEN; i+=256){
      int p2 = i / GPEN, m = i - p2*GPEN;
      int d = m / NK3, k3 = m - d*NK3;      // source layout [d*20+k3]
      float2 gv = __half22float2(gsrc[i]);
      if (k3){ gv.x *= 2.0f; gv.y *= 2.0f; } // irfft factor 2, k3>0
      Gsm[p2][k3*DV + d] = gv;
    }
  }
  if (t < 64) wsm[t] = w[t];
  __syncthreads();

  int p = t >> 6, l = t & 63;
  size_t pen = pen_base + p;

  // inverse axis-2, parity fold: E = even k3 (incl DC), O = odd k3; x = l
  float E[8], O[8];
  {
    const float4* g0 = reinterpret_cast<const float4*>(&Gsm[p][0]);
    float4 a0 = g0[0], a1 = g0[1], a2 = g0[2], a3 = g0[3];
    E[0]=a0.x; E[1]=a0.z; E[2]=a1.x; E[3]=a1.z;
    E[4]=a2.x; E[5]=a2.z; E[6]=a3.x; E[7]=a3.z;
    #pragma unroll
    for (int e=0;e<8;e++) O[e]=0.f;
  }
  for (int k3=1;k3<NK3;k3++){
    float2 tw = tws[k3*67 + l];
    const float4* gk = reinterpret_cast<const float4*>(&Gsm[p][k3*DV]);
    float4 b0 = gk[0], b1 = gk[1], b2 = gk[2], b3 = gk[3];
    float gr[8] = {b0.x,b0.z,b1.x,b1.z,b2.x,b2.z,b3.x,b3.z};
    float gi[8] = {b0.y,b0.w,b1.y,b1.w,b2.y,b2.w,b3.y,b3.w};
    if (k3 & 1){
      #pragma unroll
      for (int e=0;e<8;e++){
        O[e] = fmaf(gr[e], tw.x, O[e]);
        O[e] = fmaf(gi[e], tw.y, O[e]);
      }
    } else {
      #pragma unroll
      for (int e=0;e<8;e++){
        E[e] = fmaf(gr[e], tw.x, E[e]);
        E[e] = fmaf(gi[e], tw.y, E[e]);
      }
    }
  }

  // old v, skip, gelu
  float vvA[8], vvB[8];
  unpack_h8(*reinterpret_cast<const uint4*>(v + (pen<<10) + l*8), vvA);
  unpack_h8(*reinterpret_cast<const uint4*>(v + (pen<<10) + (l+64)*8), vvB);
  float sA[8], sB[8];
  #pragma unroll
  for (int e=0;e<8;e++){ sA[e] = E[e] + O[e]; sB[e] = E[e] - O[e]; }
  #pragma unroll
  for (int d=0;d<8;d++){
    float4 w0 = *reinterpret_cast<const float4*>(&wsm[d*8]);
    float4 w1 = *reinterpret_cast<const float4*>(&wsm[d*8+4]);
    float a = vvA[d], b = vvB[d];
    sA[0]=fmaf(a,w0.x,sA[0]); sA[1]=fmaf(a,w0.y,sA[1]); sA[2]=fmaf(a,w0.z,sA[2]); sA[3]=fmaf(a,w0.w,sA[3]);
    sA[4]=fmaf(a,w1.x,sA[4]); sA[5]=fmaf(a,w1.y,sA[5]); sA[6]=fmaf(a,w1.z,sA[6]); sA[7]=fmaf(a,w1.w,sA[7]);
    sB[0]=fmaf(b,w0.x,sB[0]); sB[1]=fmaf(b,w0.y,sB[1]); sB[2]=fmaf(b,w0.z,sB[2]); sB[3]=fmaf(b,w0.w,sB[3]);
    sB[4]=fmaf(b,w1.x,sB[4]); sB[5]=fmaf(b,w1.y,sB[5]); sB[6]=fmaf(b,w1.z,sB[6]); sB[7]=fmaf(b,w1.w,sB[7]);
  }
  #pragma unroll
  for (int e=0;e<8;e++){ sA[e] = gelu_f(sA[e]); sB[e] = gelu_f(sB[e]); }

  *reinterpret_cast<uint4*>(v + (pen<<10) + l*8)      = pack_h8(sA);
  *reinterpret_cast<uint4*>(v + (pen<<10) + (l+64)*8) = pack_h8(sB);
  #pragma unroll
  for (int e=0;e<8;e++){
    vnf[p][e][l]          = sA[e] + sB[e];
    vnf[p][e][VNF_P + l]  = sA[e] - sB[e];
  }
  __syncthreads();
  fwd_dft_phase(vnf[p], tws, g + pen*GPEN, l);
}

// --------------------- final: inv axis-2 DFT + skip + GELU + projection
__global__ __launch_bounds__(256,2) void k_final(const __half* __restrict__ v,
    const __half2* __restrict__ g, const float* __restrict__ w,
    const float* __restrict__ pw, const float* __restrict__ pb,
    float* __restrict__ out, const float2* __restrict__ twg){
  __shared__ float2 tws[NK3*67];
  __shared__ float2 Gsm[PB][GPEN];   // transposed
  __shared__ float  wsm[64];
  int t = threadIdx.x;
  size_t pen_base = (size_t)blockIdx.x * PB;
  for (int i=t; i<NK3*64; i+=256){ int k=i>>6, xx=i&63; tws[k*67+xx] = twg[i]; }
  {
    const __half2* gsrc = g + pen_base*GPEN;
    for (int i=t; i<PB*GPEN; i+=256){
      int p2 = i / GPEN, m = i - p2*GPEN;
      int d = m / NK3, k3 = m - d*NK3;
      float2 gv = __half22float2(gsrc[i]);
      if (k3){ gv.x *= 2.0f; gv.y *= 2.0f; }
      Gsm[p2][k3*DV + d] = gv;
    }
  }
  if (t < 64) wsm[t] = w[t];
  __syncthreads();

  int p = t >> 6, l = t & 63;
  size_t pen = pen_base + p;

  float E[8], O[8];
  {
    const float4* g0 = reinterpret_cast<const float4*>(&Gsm[p][0]);
    float4 a0 = g0[0], a1 = g0[1], a2 = g0[2], a3 = g0[3];
    E[0]=a0.x; E[1]=a0.z; E[2]=a1.x; E[3]=a1.z;
    E[4]=a2.x; E[5]=a2.z; E[6]=a3.x; E[7]=a3.z;
    #pragma unroll
    for (int e=0;e<8;e++) O[e]=0.f;
  }
  for (int k3=1;k3<NK3;k3++){
    float2 tw = tws[k3*67 + l];
    const float4* gk = reinterpret_cast<const float4*>(&Gsm[p][k3*DV]);
    float4 b0 = gk[0], b1 = gk[1], b2 = gk[2], b3 = gk[3];
    float gr[8] = {b0.x,b0.z,b1.x,b1.z,b2.x,b2.z,b3.x,b3.z};
    float gi[8] = {b0.y,b0.w,b1.y,b1.w,b2.y,b2.w,b3.y,b3.w};
    if (k3 & 1){
      #pragma unroll
      for (int e=0;e<8;e++){
        O[e] = fmaf(gr[e], tw.x, O[e]);
        O[e] = fmaf(gi[e], tw.y, O[e]);
      }
    } else {
      #pragma unroll
      for (int e=0;e<8;e++){
        E[e] = fmaf(gr[e], tw.x, E[e]);
        E[e] = fmaf(gi[e], tw.y, E[e]);
      }
    }
  }

  float vvA[8], vvB[8];
  unpack_h8(*reinterpret_cast<const uint4*>(v + (pen<<10) + l*8), vvA);
  unpack_h8(*reinterpret_cast<const uint4*>(v + (pen<<10) + (l+64)*8), vvB);
  float sA[8], sB[8];
  #pragma unroll
  for (int e=0;e<8;e++){ sA[e] = E[e] + O[e]; sB[e] = E[e] - O[e]; }
  #pragma unroll
  for (int d=0;d<8;d++){
    float4 w0 = *reinterpret_cast<const float4*>(&wsm[d*8]);
    float4 w1 = *reinterpret_cast<const float4*>(&wsm[d*8+4]);
    float a = vvA[d], b = vvB[d];
    sA[0]=fmaf(a,w0.x,sA[0]); sA[1]=fmaf(a,w0.y,sA[1]); sA[2]=fmaf(a,w0.z,sA[2]); sA[3]=fmaf(a,w0.w,sA[3]);
    sA[4]=fmaf(a,w1.x,sA[4]); sA[5]=fmaf(a,w1.y,sA[5]); sA[6]=fmaf(a,w1.z,sA[6]); sA[7]=fmaf(a,w1.w,sA[7]);
    sB[0]=fmaf(b,w0.x,sB[0]); sB[1]=fmaf(b,w0.y,sB[1]); sB[2]=fmaf(b,w0.z,sB[2]); sB[3]=fmaf(b,w0.w,sB[3]);
    sB[4]=fmaf(b,w1.x,sB[4]); sB[5]=fmaf(b,w1.y,sB[5]); sB[6]=fmaf(b,w1.z,sB[6]); sB[7]=fmaf(b,w1.w,sB[7]);
  }
  // gelu + projection in-register
  float accA = pb[0], accB = pb[0];
  #pragma unroll
  for (int e=0;e<8;e++){
    float pe = pw[e];                        // uniform -> scalar load
    accA = fmaf(gelu_f(sA[e]), pe, accA);
    accB = fmaf(gelu_f(sB[e]), pe, accB);
  }
  out[(pen<<7) + l]      = accA;
  out[(pen<<7) + l + 64] = accB;
}

// ------------------------------------------------------- axis-1 forward DFT
// grid (S1, 2); parity fold over x2 / x2+128 (chunk c / c+4)
__global__ __launch_bounds__(256) void k_stageB(const __half2* __restrict__ g,
    float2* __restrict__ h, const float2* __restrict__ twg){
  __shared__ unsigned int gsm[2][32*160];   // 40 KB
  int x1 = blockIdx.x;
  int k3o = blockIdx.y * 10;
  int t = threadIdx.x;
  int k2 = t >> 3, d = t & 7;
  float sgn = (k2 & 1) ? -1.0f : 1.0f;
  float ar[10], ai[10];
  #pragma unroll
  for (int j=0;j<10;j++){ ar[j]=0.f; ai[j]=0.f; }
  for (int c = 0; c < 4; c++){
    __syncthreads();
    const uint4* s0 = reinterpret_cast<const uint4*>(g + (size_t)(x1*S2 + c*32)*GPEN);
    const uint4* s1 = reinterpret_cast<const uint4*>(g + (size_t)(x1*S2 + (c+4)*32)*GPEN);
    uint4* d0 = reinterpret_cast<uint4*>(gsm[0]);
    uint4* d1 = reinterpret_cast<uint4*>(gsm[1]);
    #pragma unroll
    for (int r=0; r<5; r++){ d0[r*256 + t] = s0[r*256 + t]; d1[r*256 + t] = s1[r*256 + t]; }
    __syncthreads();
    if (t < 240){
      for (int x2l = 0; x2l < 32; x2l++){
        float2 tw = twg[k2*S2 + c*32 + x2l];
        const uint2* qlo = reinterpret_cast<const uint2*>(&gsm[0][x2l*160 + d*20 + k3o]);
        const uint2* qhi = reinterpret_cast<const uint2*>(&gsm[1][x2l*160 + d*20 + k3o]);
        #pragma unroll
        for (int jj=0; jj<5; jj++){
          uint2 ulo = qlo[jj], uhi = qhi[jj];
          float2 a0 = __half22float2(*reinterpret_cast<const __half2*>(&ulo.x));
          float2 b0 = __half22float2(*reinterpret_cast<const __half2*>(&uhi.x));
          float2 a1 = __half22float2(*reinterpret_cast<const __half2*>(&ulo.y));
          float2 b1 = __half22float2(*reinterpret_cast<const __half2*>(&uhi.y));
          float2 g0 = make_float2(fmaf(sgn, b0.x, a0.x), fmaf(sgn, b0.y, a0.y));
          float2 g1 = make_float2(fmaf(sgn, b1.x, a1.x), fmaf(sgn, b1.y, a1.y));
          cmac_fwd(ar[2*jj],   ai[2*jj],   g0, tw);
          cmac_fwd(ar[2*jj+1], ai[2*jj+1], g1, tw);
        }
      }
    }
  }
  if (t < 240){
    float2* hp = h + (size_t)((x1*NK2 + k2)*(DV*NK3) + d*NK3 + k3o);
    #pragma unroll
    for (int j=0;j<10;j++) hp[j] = make_float2(ar[j], ai[j]);
  }
}

// ------------------------------------------------------- axis-0 forward DFT
// parity fold over x1 / x1+128
__global__ __launch_bounds__(256) void k_stageC(const float2* __restrict__ h,
    float2* __restrict__ f, const float2* __restrict__ tw256){
  int idx = blockIdx.x*256 + threadIdx.x;
  if (idx >= NK1*HSLICE) return;
  int k1 = idx / HSLICE, r = idx % HSLICE;
  float sgn = (k1 & 1) ? -1.0f : 1.0f;
  float ar=0.f, ai=0.f;
  const float2* twp = &tw256[k1*S1];
  for (int x1=0; x1<128; x1++){
    float2 h1 = h[(size_t)x1*HSLICE + r];
    float2 h2 = h[(size_t)(x1+128)*HSLICE + r];
    float2 hv = make_float2(fmaf(sgn, h2.x, h1.x), fmaf(sgn, h2.y, h1.y));
    cmac_fwd(ar, ai, hv, twp[x1]);
  }
  f[idx] = make_float2(ar, ai);
}

// ------------------------------------------------------------- mode mixing
__global__ __launch_bounds__(256) void k_mix(const float2* __restrict__ f,
    const float* __restrict__ Rr, const float* __restrict__ Ri,
    float2* __restrict__ Rf){
  int idx = blockIdx.x*256 + threadIdx.x;
  if (idx >= NK1*HSLICE) return;
  int k12 = idx / (DV*NK3), r = idx % (DV*NK3);
  int e = r / NK3, k3 = r % NK3;
  const float2* fp  = &f[(size_t)k12*(DV*NK3) + k3];
  const float* rrp = &Rr[((size_t)k12*NK3 + k3)*64 + e];
  const float* rip = &Ri[((size_t)k12*NK3 + k3)*64 + e];
  float ar=0.f, ai=0.f;
  #pragma unroll
  for (int d=0; d<DV; d++){
    float2 fv = fp[d*NK3];
    float wr = rrp[d*DV], wi = rip[d*DV];
    ar = fmaf(fv.x, wr, ar); ar = fmaf(-fv.y, wi, ar);
    ai = fmaf(fv.x, wi, ai); ai = fmaf(fv.y, wr, ai);
  }
  const float sc = 1.1920928955078125e-7f; // 1/(256*256*128)
  Rf[idx] = make_float2(ar*sc, ai*sc);
}

// ------------------------------------------------------- axis-0 inverse DFT
// parity fold: one thread emits H[x1] and H[x1+128]
__global__ __launch_bounds__(256) void k_stageCi(const float2* __restrict__ Rf,
    float2* __restrict__ H, const float2* __restrict__ tw256){
  int idx = blockIdx.x*256 + threadIdx.x;   // exactly 128*4800 threads
  int x1 = idx / HSLICE, r = idx % HSLICE;
  float Er=0.f, Ei=0.f, Or=0.f, Oi=0.f;
  #pragma unroll
  for (int k1=0; k1<NK1; k1++){
    float2 a = Rf[(size_t)k1*HSLICE + r];
    float2 tw = tw256[k1*S1 + x1];
    if (k1 & 1) cmac_inv(Or, Oi, a, tw);
    else        cmac_inv(Er, Ei, a, tw);
  }
  H[(size_t)x1*HSLICE + r]        = make_float2(Er+Or, Ei+Oi);
  H[(size_t)(x1+128)*HSLICE + r]  = make_float2(Er-Or, Ei-Oi);
}

// ------------------------------------------------------- axis-1 inverse DFT
// parity fold: one thread-iter emits G[x2] and G[x2+128]
__global__ __launch_bounds__(320) void k_stageBi(const float2* __restrict__ H,
    __half2* __restrict__ G, const float2* __restrict__ twg){
  __shared__ float2 Hs[HSLICE];            // 38.4 KB
  int x1 = blockIdx.x;
  int t = threadIdx.x;                     // 320
  const float* Hf = (const float*)(H + (size_t)x1*HSLICE);
  float* Hsf = (float*)Hs;
  for (int i = t; i < HSLICE*2; i += 320) Hsf[i] = Hf[i];
  __syncthreads();
  int grp = t / 160, r = t % 160;
  for (int i = 0; i < 64; i++){
    int x2 = 2*i + grp;
    float Er=0.f, Ei=0.f, Or=0.f, Oi=0.f;
    #pragma unroll
    for (int k2=0; k2<NK2; k2++){
      float2 a = Hs[k2*160 + r];
      float2 tw = twg[k2*S2 + x2];
      if (k2 & 1) cmac_inv(Or, Oi, a, tw);
      else        cmac_inv(Er, Ei, a, tw);
    }
    size_t b = ((size_t)(x1*S2) + x2)*GPEN + r;
    G[b]                      = __floats2half2_rn(Er+Or, Ei+Oi);
    G[b + (size_t)128*GPEN]   = __floats2half2_rn(Er-Or, Ei-Oi);
  }
}

extern "C" void kernel_launch(void* const* d_in, const int* in_sizes, int n_in,
                              void* d_out, int out_size, void* d_ws, size_t ws_size,
                              hipStream_t stream){
  const float* x  = (const float*)d_in[0];
  const float* sw = (const float*)d_in[1];
  const float* sb = (const float*)d_in[2];
  const float* Rr[4] = {(const float*)d_in[3],(const float*)d_in[6],(const float*)d_in[9],(const float*)d_in[12]};
  const float* Ri[4] = {(const float*)d_in[4],(const float*)d_in[7],(const float*)d_in[10],(const float*)d_in[13]};
  const float* w[4]  = {(const float*)d_in[5],(const float*)d_in[8],(const float*)d_in[11],(const float*)d_in[14]};
  const float* pw = (const float*)d_in[15];
  const float* pb = (const float*)d_in[16];
  float* out = (float*)d_out;
  float* ws = (float*)d_ws;

  __half*  v    = (__half*)(ws + OFF_V);
  __half2* g    = (__half2*)(ws + OFF_G);
  float2* h     = (float2*)(ws + OFF_H);
  float2* f     = (float2*)(ws + OFF_F);
  float2* Rf    = (float2*)(ws + OFF_RF);
  float2* tw128 = (float2*)(ws + OFF_TW128);
  float2* tw256 = (float2*)(ws + OFF_TW256);

  k_twiddles<<<35, 256, 0, stream>>>(tw128, tw256);
  k_shallow<<<NPEN/PB, 256, 0, stream>>>(x, sw, sb, v, g, tw128);
  for (int L = 0; L < 4; L++){
    k_stageB <<<dim3(S1,2), 256, 0, stream>>>(g, h, tw256);
    k_stageC <<<(NK1*HSLICE + 255)/256, 256, 0, stream>>>(h, f, tw256);
    k_mix    <<<(NK1*HSLICE + 255)/256, 256, 0, stream>>>(f, Rr[L], Ri[L], Rf);
    k_stageCi<<<(128*HSLICE)/256, 256, 0, stream>>>(Rf, h, tw256);
    k_stageBi<<<S1, 320, 0, stream>>>(h, g, tw256);
    if (L < 3)
      k_combine<<<NPEN/PB, 256, 0, stream>>>(v, g, w[L], tw128);
    else
      k_final<<<NPEN/PB, 256, 0, stream>>>(v, g, w[L], pw, pb, out, tw128);
  }
}

// Round 10
// 1533.274 us; speedup vs baseline: 4.2228x; 4.2228x over previous
//
#include <hip/hip_runtime.h>
#include <hip/hip_fp16.h>
#include <math.h>

// Problem constants
#define S1 256
#define S2 256
#define S3 128
#define DV 8
#define NK1 30
#define NK2 30
#define NK3 20
#define NPEN (S1*S2)          // 65536 pencils along x3
#define PENC (S3*DV)          // 1024 elements per v pencil (fp16)
#define GPEN (DV*NK3)         // 160 complex per g pencil (fp16 complex)
#define GPAD 200              // padded transposed Gsm: [k3*10 + d], 16B-aligned rows
#define HSLICE (NK2*DV*NK3)   // 4800 complex per x1 slice of h (fp32)
#define PB 4                  // pencils per block in combine/shallow/final

// vnf LDS layout: [PB][DV][VNF_D] floats, parity plane at par*VNF_P
#define VNF_D 148
#define VNF_P 72

// Workspace layout in float-slots (4 bytes each) — total ~179.7 MiB
#define OFF_V     0ull
#define SZ_V      ((unsigned long long)NPEN*PENC/2)
#define OFF_G     (OFF_V + SZ_V)
#define SZ_G      ((unsigned long long)NPEN*GPEN)
#define OFF_H     (OFF_G + SZ_G)
#define SZ_H      ((unsigned long long)S1*HSLICE*2)
#define OFF_F     (OFF_H + SZ_H)
#define SZ_F      ((unsigned long long)NK1*HSLICE*2)
#define OFF_RF    (OFF_F + SZ_F)
#define OFF_TW128 (OFF_RF + SZ_F)
#define SZ_TW128  (2ull*NK3*64)
#define OFF_TW256 (OFF_TW128 + SZ_TW128)

__device__ __forceinline__ float gelu_f(float x){
  return 0.5f*x*(1.0f+erff(x*0.70710678118654752440f));
}
__device__ __forceinline__ void cmac_fwd(float& ar, float& ai, float2 a, float2 t){
  ar = fmaf(a.x, t.x, ar); ar = fmaf(-a.y, t.y, ar);
  ai = fmaf(a.x, t.y, ai); ai = fmaf(a.y, t.x, ai);
}
__device__ __forceinline__ void cmac_inv(float& ar, float& ai, float2 a, float2 t){
  ar = fmaf(a.x, t.x, ar); ar = fmaf(a.y, t.y, ar);
  ai = fmaf(a.y, t.x, ai); ai = fmaf(-a.x, t.y, ai);
}
__device__ __forceinline__ uint4 pack_h8(const float* v8){
  union { uint4 u4; __half2 h2[4]; } u;
  u.h2[0] = __floats2half2_rn(v8[0], v8[1]);
  u.h2[1] = __floats2half2_rn(v8[2], v8[3]);
  u.h2[2] = __floats2half2_rn(v8[4], v8[5]);
  u.h2[3] = __floats2half2_rn(v8[6], v8[7]);
  return u.u4;
}
__device__ __forceinline__ void unpack_h8(uint4 u4in, float* v8){
  union { uint4 u4; __half2 h2[4]; } u; u.u4 = u4in;
  #pragma unroll
  for (int q=0;q<4;q++){
    float2 f2 = __half22float2(u.h2[q]);
    v8[2*q] = f2.x; v8[2*q+1] = f2.y;
  }
}

// ---------------------------------------------------------------- twiddles
// tw128: [20][64] e^{-2pi i k x/128}, x<64 ; tw256: [30][256]
__global__ __launch_bounds__(256) void k_twiddles(float2* __restrict__ tw128,
                                                  float2* __restrict__ tw256){
  int idx = blockIdx.x*256 + threadIdx.x;
  if (idx < NK3*64){
    int k = idx >> 6, x = idx & 63;
    int m = (k*x) & 127;
    float a = -(float)m * (1.0f/64.0f);
    float s, c; sincospif(a, &s, &c);
    tw128[idx] = make_float2(c, s);   // (cos, -sin)
  }
  int j = idx - NK3*64;
  if (j >= 0 && j < NK2*S2){
    int k = j >> 8, x = j & 255;
    int m = (k*x) & 255;
    float a = -(float)m * (1.0f/128.0f);
    float s, c; sincospif(a, &s, &c);
    tw256[j] = make_float2(c, s);
  }
}

// =========================================================================
// fwd axis-2 DFT from folded vnf -> g, lanes 0..39 of each warp
// X[k3] = sum_{x<64} w_par[x] e^{-2pi i k3 x/128},  par = k3&1
// =========================================================================
__device__ __forceinline__ void fwd_dft_phase(const float (*vnfp)[VNF_D],
    const float2* tws, __half2* gout_pen, int l){
  if (l >= 40) return;
  int k3 = l % 20, dg = l / 20, par = k3 & 1;
  float ar[4] = {0,0,0,0}, ai[4] = {0,0,0,0};
  for (int x0 = 0; x0 < 64; x0 += 4){
    float4 vv[4];
    #pragma unroll
    for (int di=0; di<4; di++)
      vv[di] = *reinterpret_cast<const float4*>(&vnfp[dg*4+di][par*VNF_P + x0]);
    float2 t2[4];
    #pragma unroll
    for (int xi=0; xi<4; xi++) t2[xi] = tws[k3*67 + x0 + xi];
    #pragma unroll
    for (int di=0; di<4; di++){
      ar[di] = fmaf(vv[di].x, t2[0].x, ar[di]); ai[di] = fmaf(vv[di].x, t2[0].y, ai[di]);
      ar[di] = fmaf(vv[di].y, t2[1].x, ar[di]); ai[di] = fmaf(vv[di].y, t2[1].y, ai[di]);
      ar[di] = fmaf(vv[di].z, t2[2].x, ar[di]); ai[di] = fmaf(vv[di].z, t2[2].y, ai[di]);
      ar[di] = fmaf(vv[di].w, t2[3].x, ar[di]); ai[di] = fmaf(vv[di].w, t2[3].y, ai[di]);
    }
  }
  #pragma unroll
  for (int di=0; di<4; di++)
    gout_pen[(dg*4+di)*NK3 + k3] = __floats2half2_rn(ar[di], ai[di]);
}

// inverse axis-2 parity-folded accumulators from transposed/padded Gsm
__device__ __forceinline__ void inv_dft_EO(const float2* Gp, const float2* tws,
    int l, float* E, float* O){
  {
    const float4* g0 = reinterpret_cast<const float4*>(Gp);
    float4 a0 = g0[0], a1 = g0[1], a2 = g0[2], a3 = g0[3];
    E[0]=a0.x; E[1]=a0.z; E[2]=a1.x; E[3]=a1.z;
    E[4]=a2.x; E[5]=a2.z; E[6]=a3.x; E[7]=a3.z;
    #pragma unroll
    for (int e=0;e<8;e++) O[e]=0.f;
  }
  for (int k3=1;k3<NK3;k3++){
    float2 tw = tws[k3*67 + l];
    const float4* gk = reinterpret_cast<const float4*>(Gp + k3*10);
    float4 b0 = gk[0], b1 = gk[1], b2 = gk[2], b3 = gk[3];
    float gr[8] = {b0.x,b0.z,b1.x,b1.z,b2.x,b2.z,b3.x,b3.z};
    float gi[8] = {b0.y,b0.w,b1.y,b1.w,b2.y,b2.w,b3.y,b3.w};
    if (k3 & 1){
      #pragma unroll
      for (int e=0;e<8;e++){
        O[e] = fmaf(gr[e], tw.x, O[e]);
        O[e] = fmaf(gi[e], tw.y, O[e]);
      }
    } else {
      #pragma unroll
      for (int e=0;e<8;e++){
        E[e] = fmaf(gr[e], tw.x, E[e]);
        E[e] = fmaf(gi[e], tw.y, E[e]);
      }
    }
  }
}

// skip connection: s[e] += vv[d] * w[d][e], w broadcast from LDS
__device__ __forceinline__ void skip_add(const float* wsm, const float* vv, float* s){
  #pragma unroll 4
  for (int d=0; d<8; d++){
    float4 w0 = *reinterpret_cast<const float4*>(&wsm[d*8]);
    float4 w1 = *reinterpret_cast<const float4*>(&wsm[d*8+4]);
    float a = vv[d];
    s[0]=fmaf(a,w0.x,s[0]); s[1]=fmaf(a,w0.y,s[1]); s[2]=fmaf(a,w0.z,s[2]); s[3]=fmaf(a,w0.w,s[3]);
    s[4]=fmaf(a,w1.x,s[4]); s[5]=fmaf(a,w1.y,s[5]); s[6]=fmaf(a,w1.z,s[6]); s[7]=fmaf(a,w1.w,s[7]);
  }
}

// ------------------------------------------------- shallow lift + axis-2 DFT
// lane l owns x3 = l and l+64, all 8 channels
__global__ __launch_bounds__(256,2) void k_shallow(const float* __restrict__ x,
    const float* __restrict__ sw, const float* __restrict__ sb,
    __half* __restrict__ v, __half2* __restrict__ g,
    const float2* __restrict__ twg){
  __shared__ float2 tws[NK3*67];
  __shared__ float  vnf[PB][DV][VNF_D];
  int t = threadIdx.x;
  size_t pen_base = (size_t)blockIdx.x * PB;
  for (int i=t; i<NK3*64; i+=256){ int k=i>>6, xx=i&63; tws[k*67+xx] = twg[i]; }
  int p = t >> 6, l = t & 63;
  size_t pen = pen_base + p;
  float xA = x[(pen<<7) + l];
  float xB = x[(pen<<7) + l + 64];
  float valA[8], valB[8];
  #pragma unroll
  for (int e=0;e<8;e++){
    float we = sw[e], be = sb[e];            // uniform -> scalar loads
    valA[e] = gelu_f(fmaf(xA, we, be));
    valB[e] = gelu_f(fmaf(xB, we, be));
  }
  *reinterpret_cast<uint4*>(v + (pen<<10) + l*8)        = pack_h8(valA);
  *reinterpret_cast<uint4*>(v + (pen<<10) + (l+64)*8)   = pack_h8(valB);
  #pragma unroll
  for (int e=0;e<8;e++){
    vnf[p][e][l]          = valA[e] + valB[e];
    vnf[p][e][VNF_P + l]  = valA[e] - valB[e];
  }
  __syncthreads();
  fwd_dft_phase(vnf[p], tws, g + pen*GPEN, l);
}

// --------------------- combine: inv axis-2 DFT + skip + GELU + next fwd DFT
// A/B halves phased sequentially to keep live VGPRs < 128 (no spill, 2 blk/CU)
__global__ __launch_bounds__(256,2) void k_combine(__half* __restrict__ v,
    __half2* __restrict__ g, const float* __restrict__ w,
    const float2* __restrict__ twg){
  __shared__ float2 tws[NK3*67];
  __shared__ float  vnf[PB][DV][VNF_D];
  __shared__ float2 Gsm[PB][GPAD];   // transposed [k3*10+d], x2-scaled k3>0
  __shared__ float  wsm[64];
  int t = threadIdx.x;
  size_t pen_base = (size_t)blockIdx.x * PB;
  for (int i=t; i<NK3*64; i+=256){ int k=i>>6, xx=i&63; tws[k*67+xx] = twg[i]; }
  {
    const __half2* gsrc = g + pen_base*GPEN;
    for (int i=t; i<PB*GPEN; i+=256){
      int p2 = i / GPEN, m = i - p2*GPEN;
      int d = m / NK3, k3 = m - d*NK3;      // source layout [d*20+k3]
      float2 gv = __half22float2(gsrc[i]);
      if (k3){ gv.x *= 2.0f; gv.y *= 2.0f; } // irfft factor 2, k3>0
      Gsm[p2][k3*10 + d] = gv;
    }
  }
  if (t < 64) wsm[t] = w[t];
  __syncthreads();

  int p = t >> 6, l = t & 63;
  size_t pen = pen_base + p;

  float E[8], O[8];
  inv_dft_EO(&Gsm[p][0], tws, l, E, O);

  // ---- A half (x3 = l) ----
  float sA[8];
  {
    float vvA[8];
    unpack_h8(*reinterpret_cast<const uint4*>(v + (pen<<10) + l*8), vvA);
    #pragma unroll
    for (int e=0;e<8;e++) sA[e] = E[e] + O[e];
    skip_add(wsm, vvA, sA);
    #pragma unroll
    for (int e=0;e<8;e++) sA[e] = gelu_f(sA[e]);
    *reinterpret_cast<uint4*>(v + (pen<<10) + l*8) = pack_h8(sA);
  }
  // ---- B half (x3 = l+64) ----
  float sB[8];
  {
    float vvB[8];
    unpack_h8(*reinterpret_cast<const uint4*>(v + (pen<<10) + (l+64)*8), vvB);
    #pragma unroll
    for (int e=0;e<8;e++) sB[e] = E[e] - O[e];
    skip_add(wsm, vvB, sB);
    #pragma unroll
    for (int e=0;e<8;e++) sB[e] = gelu_f(sB[e]);
    *reinterpret_cast<uint4*>(v + (pen<<10) + (l+64)*8) = pack_h8(sB);
  }
  #pragma unroll
  for (int e=0;e<8;e++){
    vnf[p][e][l]          = sA[e] + sB[e];
    vnf[p][e][VNF_P + l]  = sA[e] - sB[e];
  }
  __syncthreads();
  fwd_dft_phase(vnf[p], tws, g + pen*GPEN, l);
}

// --------------------- final: inv axis-2 DFT + skip + GELU + projection
__global__ __launch_bounds__(256,2) void k_final(const __half* __restrict__ v,
    const __half2* __restrict__ g, const float* __restrict__ w,
    const float* __restrict__ pw, const float* __restrict__ pb,
    float* __restrict__ out, const float2* __restrict__ twg){
  __shared__ float2 tws[NK3*67];
  __shared__ float2 Gsm[PB][GPAD];   // transposed, padded
  __shared__ float  wsm[64];
  int t = threadIdx.x;
  size_t pen_base = (size_t)blockIdx.x * PB;
  for (int i=t; i<NK3*64; i+=256){ int k=i>>6, xx=i&63; tws[k*67+xx] = twg[i]; }
  {
    const __half2* gsrc = g + pen_base*GPEN;
    for (int i=t; i<PB*GPEN; i+=256){
      int p2 = i / GPEN, m = i - p2*GPEN;
      int d = m / NK3, k3 = m - d*NK3;
      float2 gv = __half22float2(gsrc[i]);
      if (k3){ gv.x *= 2.0f; gv.y *= 2.0f; }
      Gsm[p2][k3*10 + d] = gv;
    }
  }
  if (t < 64) wsm[t] = w[t];
  __syncthreads();

  int p = t >> 6, l = t & 63;
  size_t pen = pen_base + p;

  float E[8], O[8];
  inv_dft_EO(&Gsm[p][0], tws, l, E, O);

  float pb0 = pb[0];
  // ---- A half ----
  float accA;
  {
    float sA[8], vvA[8];
    unpack_h8(*reinterpret_cast<const uint4*>(v + (pen<<10) + l*8), vvA);
    #pragma unroll
    for (int e=0;e<8;e++) sA[e] = E[e] + O[e];
    skip_add(wsm, vvA, sA);
    accA = pb0;
    #pragma unroll
    for (int e=0;e<8;e++) accA = fmaf(gelu_f(sA[e]), pw[e], accA);
  }
  // ---- B half ----
  float accB;
  {
    float sB[8], vvB[8];
    unpack_h8(*reinterpret_cast<const uint4*>(v + (pen<<10) + (l+64)*8), vvB);
    #pragma unroll
    for (int e=0;e<8;e++) sB[e] = E[e] - O[e];
    skip_add(wsm, vvB, sB);
    accB = pb0;
    #pragma unroll
    for (int e=0;e<8;e++) accB = fmaf(gelu_f(sB[e]), pw[e], accB);
  }
  out[(pen<<7) + l]      = accA;
  out[(pen<<7) + l + 64] = accB;
}

// ------------------------------------------------------- axis-1 forward DFT
// grid (S1, 2); parity fold over x2 / x2+128 (chunk c / c+4)
__global__ __launch_bounds__(256) void k_stageB(const __half2* __restrict__ g,
    float2* __restrict__ h, const float2* __restrict__ twg){
  __shared__ unsigned int gsm[2][32*160];   // 40 KB
  int x1 = blockIdx.x;
  int k3o = blockIdx.y * 10;
  int t = threadIdx.x;
  int k2 = t >> 3, d = t & 7;
  float sgn = (k2 & 1) ? -1.0f : 1.0f;
  float ar[10], ai[10];
  #pragma unroll
  for (int j=0;j<10;j++){ ar[j]=0.f; ai[j]=0.f; }
  for (int c = 0; c < 4; c++){
    __syncthreads();
    const uint4* s0 = reinterpret_cast<const uint4*>(g + (size_t)(x1*S2 + c*32)*GPEN);
    const uint4* s1 = reinterpret_cast<const uint4*>(g + (size_t)(x1*S2 + (c+4)*32)*GPEN);
    uint4* d0 = reinterpret_cast<uint4*>(gsm[0]);
    uint4* d1 = reinterpret_cast<uint4*>(gsm[1]);
    #pragma unroll
    for (int r=0; r<5; r++){ d0[r*256 + t] = s0[r*256 + t]; d1[r*256 + t] = s1[r*256 + t]; }
    __syncthreads();
    if (t < 240){
      for (int x2l = 0; x2l < 32; x2l++){
        float2 tw = twg[k2*S2 + c*32 + x2l];
        const uint2* qlo = reinterpret_cast<const uint2*>(&gsm[0][x2l*160 + d*20 + k3o]);
        const uint2* qhi = reinterpret_cast<const uint2*>(&gsm[1][x2l*160 + d*20 + k3o]);
        #pragma unroll
        for (int jj=0; jj<5; jj++){
          uint2 ulo = qlo[jj], uhi = qhi[jj];
          float2 a0 = __half22float2(*reinterpret_cast<const __half2*>(&ulo.x));
          float2 b0 = __half22float2(*reinterpret_cast<const __half2*>(&uhi.x));
          float2 a1 = __half22float2(*reinterpret_cast<const __half2*>(&ulo.y));
          float2 b1 = __half22float2(*reinterpret_cast<const __half2*>(&uhi.y));
          float2 g0 = make_float2(fmaf(sgn, b0.x, a0.x), fmaf(sgn, b0.y, a0.y));
          float2 g1 = make_float2(fmaf(sgn, b1.x, a1.x), fmaf(sgn, b1.y, a1.y));
          cmac_fwd(ar[2*jj],   ai[2*jj],   g0, tw);
          cmac_fwd(ar[2*jj+1], ai[2*jj+1], g1, tw);
        }
      }
    }
  }
  if (t < 240){
    float2* hp = h + (size_t)((x1*NK2 + k2)*(DV*NK3) + d*NK3 + k3o);
    #pragma unroll
    for (int j=0;j<10;j++) hp[j] = make_float2(ar[j], ai[j]);
  }
}

// ------------------------------------------------------- axis-0 forward DFT
// parity fold over x1 / x1+128
__global__ __launch_bounds__(256) void k_stageC(const float2* __restrict__ h,
    float2* __restrict__ f, const float2* __restrict__ tw256){
  int idx = blockIdx.x*256 + threadIdx.x;
  if (idx >= NK1*HSLICE) return;
  int k1 = idx / HSLICE, r = idx % HSLICE;
  float sgn = (k1 & 1) ? -1.0f : 1.0f;
  float ar=0.f, ai=0.f;
  const float2* twp = &tw256[k1*S1];
  for (int x1=0; x1<128; x1++){
    float2 h1 = h[(size_t)x1*HSLICE + r];
    float2 h2 = h[(size_t)(x1+128)*HSLICE + r];
    float2 hv = make_float2(fmaf(sgn, h2.x, h1.x), fmaf(sgn, h2.y, h1.y));
    cmac_fwd(ar, ai, hv, twp[x1]);
  }
  f[idx] = make_float2(ar, ai);
}

// ------------------------------------------------------------- mode mixing
__global__ __launch_bounds__(256) void k_mix(const float2* __restrict__ f,
    const float* __restrict__ Rr, const float* __restrict__ Ri,
    float2* __restrict__ Rf){
  int idx = blockIdx.x*256 + threadIdx.x;
  if (idx >= NK1*HSLICE) return;
  int k12 = idx / (DV*NK3), r = idx % (DV*NK3);
  int e = r / NK3, k3 = r % NK3;
  const float2* fp  = &f[(size_t)k12*(DV*NK3) + k3];
  const float* rrp = &Rr[((size_t)k12*NK3 + k3)*64 + e];
  const float* rip = &Ri[((size_t)k12*NK3 + k3)*64 + e];
  float ar=0.f, ai=0.f;
  #pragma unroll
  for (int d=0; d<DV; d++){
    float2 fv = fp[d*NK3];
    float wr = rrp[d*DV], wi = rip[d*DV];
    ar = fmaf(fv.x, wr, ar); ar = fmaf(-fv.y, wi, ar);
    ai = fmaf(fv.x, wi, ai); ai = fmaf(fv.y, wr, ai);
  }
  const float sc = 1.1920928955078125e-7f; // 1/(256*256*128)
  Rf[idx] = make_float2(ar*sc, ai*sc);
}

// ------------------------------------------------------- axis-0 inverse DFT
// parity fold: one thread emits H[x1] and H[x1+128]
__global__ __launch_bounds__(256) void k_stageCi(const float2* __restrict__ Rf,
    float2* __restrict__ H, const float2* __restrict__ tw256){
  int idx = blockIdx.x*256 + threadIdx.x;   // exactly 128*4800 threads
  int x1 = idx / HSLICE, r = idx % HSLICE;
  float Er=0.f, Ei=0.f, Or=0.f, Oi=0.f;
  #pragma unroll
  for (int k1=0; k1<NK1; k1++){
    float2 a = Rf[(size_t)k1*HSLICE + r];
    float2 tw = tw256[k1*S1 + x1];
    if (k1 & 1) cmac_inv(Or, Oi, a, tw);
    else        cmac_inv(Er, Ei, a, tw);
  }
  H[(size_t)x1*HSLICE + r]        = make_float2(Er+Or, Ei+Oi);
  H[(size_t)(x1+128)*HSLICE + r]  = make_float2(Er-Or, Ei-Oi);
}

// ------------------------------------------------------- axis-1 inverse DFT
// parity fold: one thread-iter emits G[x2] and G[x2+128]
__global__ __launch_bounds__(320) void k_stageBi(const float2* __restrict__ H,
    __half2* __restrict__ G, const float2* __restrict__ twg){
  __shared__ float2 Hs[HSLICE];            // 38.4 KB
  int x1 = blockIdx.x;
  int t = threadIdx.x;                     // 320
  const float* Hf = (const float*)(H + (size_t)x1*HSLICE);
  float* Hsf = (float*)Hs;
  for (int i = t; i < HSLICE*2; i += 320) Hsf[i] = Hf[i];
  __syncthreads();
  int grp = t / 160, r = t % 160;
  for (int i = 0; i < 64; i++){
    int x2 = 2*i + grp;
    float Er=0.f, Ei=0.f, Or=0.f, Oi=0.f;
    #pragma unroll
    for (int k2=0; k2<NK2; k2++){
      float2 a = Hs[k2*160 + r];
      float2 tw = twg[k2*S2 + x2];
      if (k2 & 1) cmac_inv(Or, Oi, a, tw);
      else        cmac_inv(Er, Ei, a, tw);
    }
    size_t b = ((size_t)(x1*S2) + x2)*GPEN + r;
    G[b]                      = __floats2half2_rn(Er+Or, Ei+Oi);
    G[b + (size_t)128*GPEN]   = __floats2half2_rn(Er-Or, Ei-Oi);
  }
}

extern "C" void kernel_launch(void* const* d_in, const int* in_sizes, int n_in,
                              void* d_out, int out_size, void* d_ws, size_t ws_size,
                              hipStream_t stream){
  const float* x  = (const float*)d_in[0];
  const float* sw = (const float*)d_in[1];
  const float* sb = (const float*)d_in[2];
  const float* Rr[4] = {(const float*)d_in[3],(const float*)d_in[6],(const float*)d_in[9],(const float*)d_in[12]};
  const float* Ri[4] = {(const float*)d_in[4],(const float*)d_in[7],(const float*)d_in[10],(const float*)d_in[13]};
  const float* w[4]  = {(const float*)d_in[5],(const float*)d_in[8],(const float*)d_in[11],(const float*)d_in[14]};
  const float* pw = (const float*)d_in[15];
  const float* pb = (const float*)d_in[16];
  float* out = (float*)d_out;
  float* ws = (float*)d_ws;

  __half*  v    = (__half*)(ws + OFF_V);
  __half2* g    = (__half2*)(ws + OFF_G);
  float2* h     = (float2*)(ws + OFF_H);
  float2* f     = (float2*)(ws + OFF_F);
  float2* Rf    = (float2*)(ws + OFF_RF);
  float2* tw128 = (float2*)(ws + OFF_TW128);
  float2* tw256 = (float2*)(ws + OFF_TW256);

  k_twiddles<<<35, 256, 0, stream>>>(tw128, tw256);
  k_shallow<<<NPEN/PB, 256, 0, stream>>>(x, sw, sb, v, g, tw128);
  for (int L = 0; L < 4; L++){
    k_stageB <<<dim3(S1,2), 256, 0, stream>>>(g, h, tw256);
    k_stageC <<<(NK1*HSLICE + 255)/256, 256, 0, stream>>>(h, f, tw256);
    k_mix    <<<(NK1*HSLICE + 255)/256, 256, 0, stream>>>(f, Rr[L], Ri[L], Rf);
    k_stageCi<<<(128*HSLICE)/256, 256, 0, stream>>>(Rf, h, tw256);
    k_stageBi<<<S1, 320, 0, stream>>>(h, g, tw256);
    if (L < 3)
      k_combine<<<NPEN/PB, 256, 0, stream>>>(v, g, w[L], tw128);
    else
      k_final<<<NPEN/PB, 256, 0, stream>>>(v, g, w[L], pw, pb, out, tw128);
  }
}

// Round 11
// 1317.317 us; speedup vs baseline: 4.9151x; 1.1639x over previous
//
#include <hip/hip_runtime.h>
#include <hip/hip_fp16.h>
#include <math.h>

// Problem constants
#define S1 256
#define S2 256
#define S3 128
#define DV 8
#define NK1 30
#define NK2 30
#define NK3 20
#define NPEN (S1*S2)          // 65536 pencils along x3
#define PENC (S3*DV)          // 1024 elements per v pencil (fp16)
#define GPEN (DV*NK3)         // 160 complex per g pencil (fp16 complex)
#define GPAD 200              // padded transposed Gsm: [k3*10 + d]
#define HSLICE (NK2*DV*NK3)   // 4800 complex per x1 slice of h (fp32)
#define PB 4                  // pencils per block in combine/shallow/final

// vnf LDS layout: [PB][DV][VNF_D] floats, parity plane at par*VNF_P
#define VNF_D 148
#define VNF_P 72

// Workspace layout in float-slots (4 bytes each) — total ~179.7 MiB
#define OFF_V     0ull
#define SZ_V      ((unsigned long long)NPEN*PENC/2)
#define OFF_G     (OFF_V + SZ_V)
#define SZ_G      ((unsigned long long)NPEN*GPEN)
#define OFF_H     (OFF_G + SZ_G)
#define SZ_H      ((unsigned long long)S1*HSLICE*2)
#define OFF_F     (OFF_H + SZ_H)
#define SZ_F      ((unsigned long long)NK1*HSLICE*2)
#define OFF_RF    (OFF_F + SZ_F)
#define OFF_TW128 (OFF_RF + SZ_F)
#define SZ_TW128  (2ull*NK3*64)
#define OFF_TW256 (OFF_TW128 + SZ_TW128)

__device__ __forceinline__ float gelu_f(float x){
  return 0.5f*x*(1.0f+erff(x*0.70710678118654752440f));
}
__device__ __forceinline__ void cmac_fwd(float& ar, float& ai, float2 a, float2 t){
  ar = fmaf(a.x, t.x, ar); ar = fmaf(-a.y, t.y, ar);
  ai = fmaf(a.x, t.y, ai); ai = fmaf(a.y, t.x, ai);
}
__device__ __forceinline__ void cmac_inv(float& ar, float& ai, float2 a, float2 t){
  ar = fmaf(a.x, t.x, ar); ar = fmaf(a.y, t.y, ar);
  ai = fmaf(a.y, t.x, ai); ai = fmaf(-a.x, t.y, ai);
}
__device__ __forceinline__ uint4 pack_h8(const float* v8){
  union { uint4 u4; __half2 h2[4]; } u;
  u.h2[0] = __floats2half2_rn(v8[0], v8[1]);
  u.h2[1] = __floats2half2_rn(v8[2], v8[3]);
  u.h2[2] = __floats2half2_rn(v8[4], v8[5]);
  u.h2[3] = __floats2half2_rn(v8[6], v8[7]);
  return u.u4;
}
__device__ __forceinline__ void unpack_h8(uint4 u4in, float* v8){
  union { uint4 u4; __half2 h2[4]; } u; u.u4 = u4in;
  #pragma unroll
  for (int q=0;q<4;q++){
    float2 f2 = __half22float2(u.h2[q]);
    v8[2*q] = f2.x; v8[2*q+1] = f2.y;
  }
}

// ---------------------------------------------------------------- twiddles
// tw128: [20][64] e^{-2pi i k x/128}, x<64 ; tw256: [30][256]
__global__ __launch_bounds__(256) void k_twiddles(float2* __restrict__ tw128,
                                                  float2* __restrict__ tw256){
  int idx = blockIdx.x*256 + threadIdx.x;
  if (idx < NK3*64){
    int k = idx >> 6, x = idx & 63;
    int m = (k*x) & 127;
    float a = -(float)m * (1.0f/64.0f);
    float s, c; sincospif(a, &s, &c);
    tw128[idx] = make_float2(c, s);   // (cos, -sin)
  }
  int j = idx - NK3*64;
  if (j >= 0 && j < NK2*S2){
    int k = j >> 8, x = j & 255;
    int m = (k*x) & 255;
    float a = -(float)m * (1.0f/128.0f);
    float s, c; sincospif(a, &s, &c);
    tw256[j] = make_float2(c, s);
  }
}

// =========================================================================
// fwd axis-2 DFT from folded vnf -> g, lanes 0..39 of each warp
// X[k3] = sum_{x<64} w_par[x] e^{-2pi i k3 x/128},  par = k3&1
// =========================================================================
__device__ __forceinline__ void fwd_dft_phase(const float (*vnfp)[VNF_D],
    const float2* tws, __half2* gout_pen, int l){
  if (l >= 40) return;
  int k3 = l % 20, dg = l / 20, par = k3 & 1;
  float ar[4] = {0,0,0,0}, ai[4] = {0,0,0,0};
  for (int x0 = 0; x0 < 64; x0 += 4){
    float4 vv[4];
    #pragma unroll
    for (int di=0; di<4; di++)
      vv[di] = *reinterpret_cast<const float4*>(&vnfp[dg*4+di][par*VNF_P + x0]);
    float2 t2[4];
    #pragma unroll
    for (int xi=0; xi<4; xi++) t2[xi] = tws[k3*67 + x0 + xi];
    #pragma unroll
    for (int di=0; di<4; di++){
      ar[di] = fmaf(vv[di].x, t2[0].x, ar[di]); ai[di] = fmaf(vv[di].x, t2[0].y, ai[di]);
      ar[di] = fmaf(vv[di].y, t2[1].x, ar[di]); ai[di] = fmaf(vv[di].y, t2[1].y, ai[di]);
      ar[di] = fmaf(vv[di].z, t2[2].x, ar[di]); ai[di] = fmaf(vv[di].z, t2[2].y, ai[di]);
      ar[di] = fmaf(vv[di].w, t2[3].x, ar[di]); ai[di] = fmaf(vv[di].w, t2[3].y, ai[di]);
    }
  }
  #pragma unroll
  for (int di=0; di<4; di++)
    gout_pen[(dg*4+di)*NK3 + k3] = __floats2half2_rn(ar[di], ai[di]);
}

// inverse axis-2 parity-folded accumulators from transposed/padded Gsm
__device__ __forceinline__ void inv_dft_EO(const float2* Gp, const float2* tws,
    int l, float* E, float* O){
  {
    const float4* g0 = reinterpret_cast<const float4*>(Gp);
    float4 a0 = g0[0], a1 = g0[1], a2 = g0[2], a3 = g0[3];
    E[0]=a0.x; E[1]=a0.z; E[2]=a1.x; E[3]=a1.z;
    E[4]=a2.x; E[5]=a2.z; E[6]=a3.x; E[7]=a3.z;
    #pragma unroll
    for (int e=0;e<8;e++) O[e]=0.f;
  }
  for (int k3=1;k3<NK3;k3++){
    float2 tw = tws[k3*67 + l];
    const float4* gk = reinterpret_cast<const float4*>(Gp + k3*10);
    float4 b0 = gk[0], b1 = gk[1], b2 = gk[2], b3 = gk[3];
    float gr[8] = {b0.x,b0.z,b1.x,b1.z,b2.x,b2.z,b3.x,b3.z};
    float gi[8] = {b0.y,b0.w,b1.y,b1.w,b2.y,b2.w,b3.y,b3.w};
    if (k3 & 1){
      #pragma unroll
      for (int e=0;e<8;e++){
        O[e] = fmaf(gr[e], tw.x, O[e]);
        O[e] = fmaf(gi[e], tw.y, O[e]);
      }
    } else {
      #pragma unroll
      for (int e=0;e<8;e++){
        E[e] = fmaf(gr[e], tw.x, E[e]);
        E[e] = fmaf(gi[e], tw.y, E[e]);
      }
    }
  }
}

// skip connection: s[e] += vv[d] * w[d][e], w broadcast from LDS
__device__ __forceinline__ void skip_add(const float* wsm, const float* vv, float* s){
  #pragma unroll 4
  for (int d=0; d<8; d++){
    float4 w0 = *reinterpret_cast<const float4*>(&wsm[d*8]);
    float4 w1 = *reinterpret_cast<const float4*>(&wsm[d*8+4]);
    float a = vv[d];
    s[0]=fmaf(a,w0.x,s[0]); s[1]=fmaf(a,w0.y,s[1]); s[2]=fmaf(a,w0.z,s[2]); s[3]=fmaf(a,w0.w,s[3]);
    s[4]=fmaf(a,w1.x,s[4]); s[5]=fmaf(a,w1.y,s[5]); s[6]=fmaf(a,w1.z,s[6]); s[7]=fmaf(a,w1.w,s[7]);
  }
}

// ------------------------------------------------- shallow lift + axis-2 DFT
// lane l owns x3 = l and l+64, all 8 channels
__global__ __launch_bounds__(256,2) void k_shallow(const float* __restrict__ x,
    const float* __restrict__ sw, const float* __restrict__ sb,
    __half* __restrict__ v, __half2* __restrict__ g,
    const float2* __restrict__ twg){
  __shared__ float2 tws[NK3*67];
  __shared__ float  vnf[PB][DV][VNF_D];
  int t = threadIdx.x;
  size_t pen_base = (size_t)blockIdx.x * PB;
  for (int i=t; i<NK3*64; i+=256){ int k=i>>6, xx=i&63; tws[k*67+xx] = twg[i]; }
  int p = t >> 6, l = t & 63;
  size_t pen = pen_base + p;
  float xA = x[(pen<<7) + l];
  float xB = x[(pen<<7) + l + 64];
  float valA[8], valB[8];
  #pragma unroll
  for (int e=0;e<8;e++){
    float we = sw[e], be = sb[e];            // uniform -> scalar loads
    valA[e] = gelu_f(fmaf(xA, we, be));
    valB[e] = gelu_f(fmaf(xB, we, be));
  }
  *reinterpret_cast<uint4*>(v + (pen<<10) + l*8)        = pack_h8(valA);
  *reinterpret_cast<uint4*>(v + (pen<<10) + (l+64)*8)   = pack_h8(valB);
  #pragma unroll
  for (int e=0;e<8;e++){
    vnf[p][e][l]          = valA[e] + valB[e];
    vnf[p][e][VNF_P + l]  = valA[e] - valB[e];
  }
  __syncthreads();
  fwd_dft_phase(vnf[p], tws, g + pen*GPEN, l);
}

// --------------------- combine: inv axis-2 DFT + skip + GELU + next fwd DFT
// A/B halves phased sequentially to keep live VGPRs < 128 (no spill)
__global__ __launch_bounds__(256,2) void k_combine(__half* __restrict__ v,
    __half2* __restrict__ g, const float* __restrict__ w,
    const float2* __restrict__ twg){
  __shared__ float2 tws[NK3*67];
  __shared__ float  vnf[PB][DV][VNF_D];
  __shared__ float2 Gsm[PB][GPAD];   // transposed [k3*10+d], x2-scaled k3>0
  __shared__ float  wsm[64];
  int t = threadIdx.x;
  size_t pen_base = (size_t)blockIdx.x * PB;
  for (int i=t; i<NK3*64; i+=256){ int k=i>>6, xx=i&63; tws[k*67+xx] = twg[i]; }
  {
    const __half2* gsrc = g + pen_base*GPEN;
    for (int i=t; i<PB*GPEN; i+=256){
      int p2 = i / GPEN, m = i - p2*GPEN;
      int d = m / NK3, k3 = m - d*NK3;      // source layout [d*20+k3]
      float2 gv = __half22float2(gsrc[i]);
      if (k3){ gv.x *= 2.0f; gv.y *= 2.0f; } // irfft factor 2, k3>0
      Gsm[p2][k3*10 + d] = gv;
    }
  }
  if (t < 64) wsm[t] = w[t];
  __syncthreads();

  int p = t >> 6, l = t & 63;
  size_t pen = pen_base + p;

  float E[8], O[8];
  inv_dft_EO(&Gsm[p][0], tws, l, E, O);

  // ---- A half (x3 = l) ----
  float sA[8];
  {
    float vvA[8];
    unpack_h8(*reinterpret_cast<const uint4*>(v + (pen<<10) + l*8), vvA);
    #pragma unroll
    for (int e=0;e<8;e++) sA[e] = E[e] + O[e];
    skip_add(wsm, vvA, sA);
    #pragma unroll
    for (int e=0;e<8;e++) sA[e] = gelu_f(sA[e]);
    *reinterpret_cast<uint4*>(v + (pen<<10) + l*8) = pack_h8(sA);
  }
  // ---- B half (x3 = l+64) ----
  float sB[8];
  {
    float vvB[8];
    unpack_h8(*reinterpret_cast<const uint4*>(v + (pen<<10) + (l+64)*8), vvB);
    #pragma unroll
    for (int e=0;e<8;e++) sB[e] = E[e] - O[e];
    skip_add(wsm, vvB, sB);
    #pragma unroll
    for (int e=0;e<8;e++) sB[e] = gelu_f(sB[e]);
    *reinterpret_cast<uint4*>(v + (pen<<10) + (l+64)*8) = pack_h8(sB);
  }
  #pragma unroll
  for (int e=0;e<8;e++){
    vnf[p][e][l]          = sA[e] + sB[e];
    vnf[p][e][VNF_P + l]  = sA[e] - sB[e];
  }
  __syncthreads();
  fwd_dft_phase(vnf[p], tws, g + pen*GPEN, l);
}

// --------------------- final: inv axis-2 DFT + skip + GELU + projection
__global__ __launch_bounds__(256,2) void k_final(const __half* __restrict__ v,
    const __half2* __restrict__ g, const float* __restrict__ w,
    const float* __restrict__ pw, const float* __restrict__ pb,
    float* __restrict__ out, const float2* __restrict__ twg){
  __shared__ float2 tws[NK3*67];
  __shared__ float2 Gsm[PB][GPAD];   // transposed, padded
  __shared__ float  wsm[64];
  int t = threadIdx.x;
  size_t pen_base = (size_t)blockIdx.x * PB;
  for (int i=t; i<NK3*64; i+=256){ int k=i>>6, xx=i&63; tws[k*67+xx] = twg[i]; }
  {
    const __half2* gsrc = g + pen_base*GPEN;
    for (int i=t; i<PB*GPEN; i+=256){
      int p2 = i / GPEN, m = i - p2*GPEN;
      int d = m / NK3, k3 = m - d*NK3;
      float2 gv = __half22float2(gsrc[i]);
      if (k3){ gv.x *= 2.0f; gv.y *= 2.0f; }
      Gsm[p2][k3*10 + d] = gv;
    }
  }
  if (t < 64) wsm[t] = w[t];
  __syncthreads();

  int p = t >> 6, l = t & 63;
  size_t pen = pen_base + p;

  float E[8], O[8];
  inv_dft_EO(&Gsm[p][0], tws, l, E, O);

  float pb0 = pb[0];
  // ---- A half ----
  float accA;
  {
    float sA[8], vvA[8];
    unpack_h8(*reinterpret_cast<const uint4*>(v + (pen<<10) + l*8), vvA);
    #pragma unroll
    for (int e=0;e<8;e++) sA[e] = E[e] + O[e];
    skip_add(wsm, vvA, sA);
    accA = pb0;
    #pragma unroll
    for (int e=0;e<8;e++) accA = fmaf(gelu_f(sA[e]), pw[e], accA);
  }
  // ---- B half ----
  float accB;
  {
    float sB[8], vvB[8];
    unpack_h8(*reinterpret_cast<const uint4*>(v + (pen<<10) + (l+64)*8), vvB);
    #pragma unroll
    for (int e=0;e<8;e++) sB[e] = E[e] - O[e];
    skip_add(wsm, vvB, sB);
    accB = pb0;
    #pragma unroll
    for (int e=0;e<8;e++) accB = fmaf(gelu_f(sB[e]), pw[e], accB);
  }
  out[(pen<<7) + l]      = accA;
  out[(pen<<7) + l + 64] = accB;
}

// ------------------------------------------------------- axis-1 forward DFT
// grid (S1, 2); parity fold over x2 / x2+128 (chunk c / c+4)
__global__ __launch_bounds__(256) void k_stageB(const __half2* __restrict__ g,
    float2* __restrict__ h, const float2* __restrict__ twg){
  __shared__ unsigned int gsm[2][32*160];   // 40 KB
  int x1 = blockIdx.x;
  int k3o = blockIdx.y * 10;
  int t = threadIdx.x;
  int k2 = t >> 3, d = t & 7;
  float sgn = (k2 & 1) ? -1.0f : 1.0f;
  float ar[10], ai[10];
  #pragma unroll
  for (int j=0;j<10;j++){ ar[j]=0.f; ai[j]=0.f; }
  for (int c = 0; c < 4; c++){
    __syncthreads();
    const uint4* s0 = reinterpret_cast<const uint4*>(g + (size_t)(x1*S2 + c*32)*GPEN);
    const uint4* s1 = reinterpret_cast<const uint4*>(g + (size_t)(x1*S2 + (c+4)*32)*GPEN);
    uint4* d0 = reinterpret_cast<uint4*>(gsm[0]);
    uint4* d1 = reinterpret_cast<uint4*>(gsm[1]);
    #pragma unroll
    for (int r=0; r<5; r++){ d0[r*256 + t] = s0[r*256 + t]; d1[r*256 + t] = s1[r*256 + t]; }
    __syncthreads();
    if (t < 240){
      for (int x2l = 0; x2l < 32; x2l++){
        float2 tw = twg[k2*S2 + c*32 + x2l];
        const uint2* qlo = reinterpret_cast<const uint2*>(&gsm[0][x2l*160 + d*20 + k3o]);
        const uint2* qhi = reinterpret_cast<const uint2*>(&gsm[1][x2l*160 + d*20 + k3o]);
        #pragma unroll
        for (int jj=0; jj<5; jj++){
          uint2 ulo = qlo[jj], uhi = qhi[jj];
          float2 a0 = __half22float2(*reinterpret_cast<const __half2*>(&ulo.x));
          float2 b0 = __half22float2(*reinterpret_cast<const __half2*>(&uhi.x));
          float2 a1 = __half22float2(*reinterpret_cast<const __half2*>(&ulo.y));
          float2 b1 = __half22float2(*reinterpret_cast<const __half2*>(&uhi.y));
          float2 g0 = make_float2(fmaf(sgn, b0.x, a0.x), fmaf(sgn, b0.y, a0.y));
          float2 g1 = make_float2(fmaf(sgn, b1.x, a1.x), fmaf(sgn, b1.y, a1.y));
          cmac_fwd(ar[2*jj],   ai[2*jj],   g0, tw);
          cmac_fwd(ar[2*jj+1], ai[2*jj+1], g1, tw);
        }
      }
    }
  }
  if (t < 240){
    float2* hp = h + (size_t)((x1*NK2 + k2)*(DV*NK3) + d*NK3 + k3o);
    #pragma unroll
    for (int j=0;j<10;j++) hp[j] = make_float2(ar[j], ai[j]);
  }
}

// --------------------- fused axis-0 forward DFT + mode mix (f kept in LDS)
// block = (k1, k2), 160 threads; thread r = d*20+k3 for stageC, e*20+k3 for mix
__global__ __launch_bounds__(160) void k_specC(const float2* __restrict__ h,
    const float* __restrict__ Rr, const float* __restrict__ Ri,
    float2* __restrict__ Rf, const float2* __restrict__ tw256){
  __shared__ float2 fsm[160];
  int k1 = blockIdx.x, k2 = blockIdx.y;
  int r = threadIdx.x;
  float sgn = (k1 & 1) ? -1.0f : 1.0f;
  float ar=0.f, ai=0.f;
  const float2* twp = &tw256[k1*S1];
  const float2* hp = h + k2*(DV*NK3) + r;
  for (int x1=0; x1<128; x1++){
    float2 h1 = hp[(size_t)x1*HSLICE];
    float2 h2 = hp[(size_t)(x1+128)*HSLICE];
    float2 hv = make_float2(fmaf(sgn, h2.x, h1.x), fmaf(sgn, h2.y, h1.y));
    cmac_fwd(ar, ai, hv, twp[x1]);
  }
  fsm[r] = make_float2(ar, ai);
  __syncthreads();
  int e = r / NK3, k3 = r % NK3;
  int k12 = k1*NK2 + k2;
  const float* rrp = &Rr[((size_t)k12*NK3 + k3)*64 + e];
  const float* rip = &Ri[((size_t)k12*NK3 + k3)*64 + e];
  float br=0.f, bi=0.f;
  #pragma unroll
  for (int d=0; d<DV; d++){
    float2 fv = fsm[d*NK3 + k3];
    float wr = rrp[d*DV], wi = rip[d*DV];
    br = fmaf(fv.x, wr, br); br = fmaf(-fv.y, wi, br);
    bi = fmaf(fv.x, wi, bi); bi = fmaf(fv.y, wr, bi);
  }
  const float sc = 1.1920928955078125e-7f; // 1/(256*256*128)
  Rf[(size_t)k12*(DV*NK3) + r] = make_float2(br*sc, bi*sc);
}

// ------------------------------------------------------- axis-0 inverse DFT
// parity fold: one thread emits H[x1] and H[x1+128]
__global__ __launch_bounds__(256) void k_stageCi(const float2* __restrict__ Rf,
    float2* __restrict__ H, const float2* __restrict__ tw256){
  int idx = blockIdx.x*256 + threadIdx.x;   // exactly 128*4800 threads
  int x1 = idx / HSLICE, r = idx % HSLICE;
  float Er=0.f, Ei=0.f, Or=0.f, Oi=0.f;
  #pragma unroll
  for (int k1=0; k1<NK1; k1++){
    float2 a = Rf[(size_t)k1*HSLICE + r];
    float2 tw = tw256[k1*S1 + x1];
    if (k1 & 1) cmac_inv(Or, Oi, a, tw);
    else        cmac_inv(Er, Ei, a, tw);
  }
  H[(size_t)x1*HSLICE + r]        = make_float2(Er+Or, Ei+Oi);
  H[(size_t)(x1+128)*HSLICE + r]  = make_float2(Er-Or, Ei-Oi);
}

// ------------------------------------------------------- axis-1 inverse DFT
// grid (S1,2): block = (x1, x2-quarter-pair); LDS-staged twiddles; parity
// fold emits G[x2] and G[x2+128]
__global__ __launch_bounds__(320) void k_stageBi(const float2* __restrict__ H,
    __half2* __restrict__ G, const float2* __restrict__ twg){
  __shared__ float2 Hs[HSLICE];            // 38.4 KB
  __shared__ float2 twl[NK2*64];           // 15 KB
  int x1 = blockIdx.x;
  int ybeg = blockIdx.y * 64;              // x2 base for this block
  int t = threadIdx.x;                     // 320
  const float* Hf = (const float*)(H + (size_t)x1*HSLICE);
  float* Hsf = (float*)Hs;
  for (int i = t; i < HSLICE*2; i += 320) Hsf[i] = Hf[i];
  for (int i = t; i < NK2*64; i += 320){
    int k2 = i >> 6, j = i & 63;
    twl[i] = twg[k2*S2 + ybeg + j];
  }
  __syncthreads();
  int grp = t / 160, r = t % 160;
  for (int ii = 0; ii < 32; ii++){
    int j = 2*ii + grp;                    // local x2 in [0,64)
    int x2 = ybeg + j;
    float Er=0.f, Ei=0.f, Or=0.f, Oi=0.f;
    #pragma unroll
    for (int k2=0; k2<NK2; k2++){
      float2 a = Hs[k2*160 + r];
      float2 tw = twl[k2*64 + j];
      if (k2 & 1) cmac_inv(Or, Oi, a, tw);
      else        cmac_inv(Er, Ei, a, tw);
    }
    size_t b = ((size_t)(x1*S2) + x2)*GPEN + r;
    G[b]                      = __floats2half2_rn(Er+Or, Ei+Oi);
    G[b + (size_t)128*GPEN]   = __floats2half2_rn(Er-Or, Ei-Oi);
  }
}

extern "C" void kernel_launch(void* const* d_in, const int* in_sizes, int n_in,
                              void* d_out, int out_size, void* d_ws, size_t ws_size,
                              hipStream_t stream){
  const float* x  = (const float*)d_in[0];
  const float* sw = (const float*)d_in[1];
  const float* sb = (const float*)d_in[2];
  const float* Rr[4] = {(const float*)d_in[3],(const float*)d_in[6],(const float*)d_in[9],(const float*)d_in[12]};
  const float* Ri[4] = {(const float*)d_in[4],(const float*)d_in[7],(const float*)d_in[10],(const float*)d_in[13]};
  const float* w[4]  = {(const float*)d_in[5],(const float*)d_in[8],(const float*)d_in[11],(const float*)d_in[14]};
  const float* pw = (const float*)d_in[15];
  const float* pb = (const float*)d_in[16];
  float* out = (float*)d_out;
  float* ws = (float*)d_ws;

  __half*  v    = (__half*)(ws + OFF_V);
  __half2* g    = (__half2*)(ws + OFF_G);
  float2* h     = (float2*)(ws + OFF_H);
  float2* Rf    = (float2*)(ws + OFF_RF);
  float2* tw128 = (float2*)(ws + OFF_TW128);
  float2* tw256 = (float2*)(ws + OFF_TW256);

  k_twiddles<<<35, 256, 0, stream>>>(tw128, tw256);
  k_shallow<<<NPEN/PB, 256, 0, stream>>>(x, sw, sb, v, g, tw128);
  for (int L = 0; L < 4; L++){
    k_stageB <<<dim3(S1,2), 256, 0, stream>>>(g, h, tw256);
    k_specC  <<<dim3(NK1,NK2), 160, 0, stream>>>(h, Rr[L], Ri[L], Rf, tw256);
    k_stageCi<<<(128*HSLICE)/256, 256, 0, stream>>>(Rf, h, tw256);
    k_stageBi<<<dim3(S1,2), 320, 0, stream>>>(h, g, tw256);
    if (L < 3)
      k_combine<<<NPEN/PB, 256, 0, stream>>>(v, g, w[L], tw128);
    else
      k_final<<<NPEN/PB, 256, 0, stream>>>(v, g, w[L], pw, pb, out, tw128);
  }
}